// Round 6
// baseline (51.325 us; speedup 1.0000x reference)
//
#include <hip/hip_runtime.h>

#define NOUT 83
#define NHEART 27
#define NLUNG 28

// One fused kernel. Block: 576 threads (9 waves), owns 4 volumes.
// Grid: B/4 = 1024 blocks -> 3 blocks/CU resident = 27 waves/CU (84%).
// Phase 1: 4*144 = 576 quad positions, exactly one per thread, 15 loads.
// Phase 2: 36 groups x 16 lanes; group g handles rows o = g+36k (k<3) x 4 vols.
__global__ __launch_bounds__(576, 7) void bodyavg_fused4(
    const float4* __restrict__ x4,   // [B*2160] quads
    const float* __restrict__ dzh,   // [27,16]
    const float* __restrict__ dzl,   // [28,16]
    const float4* __restrict__ fcw4, // [83,144] quads
    const float* __restrict__ fcb,   // [83]
    float* __restrict__ out,         // [B,83]
    int B)
{
    __shared__ float  attn_lds[NOUT * 17];
    __shared__ float4 xms[4 * 144];          // mean feats, 4 volumes

    const int tid = threadIdx.x;
    const int blk = blockIdx.x;
    const int b0  = blk * 4;

    // ---- Phase 0: channel softmax for 83 disease rows ----
    if (tid < NOUT) {
        const int o = tid;
        const float* row = (o < NHEART) ? (dzh + o * 16)
                                        : (dzl + ((o - NHEART) % NLUNG) * 16);
        float vals[16];
        #pragma unroll
        for (int c = 0; c < 16; ++c) vals[c] = row[c];
        float m = vals[0];
        #pragma unroll
        for (int c = 1; c < 16; ++c) m = fmaxf(m, vals[c]);
        float s = 0.f;
        #pragma unroll
        for (int c = 0; c < 16; ++c) { vals[c] = expf(vals[c] - m); s += vals[c]; }
        const float inv = 1.0f / s;
        #pragma unroll
        for (int c = 0; c < 16; ++c) attn_lds[o * 17 + c] = vals[c] * inv;
    }

    // ---- Phase 1: slice-mean, one quad position per thread ----
    {
        const int v = tid / 144;             // 0..3
        const int q = tid - v * 144;         // 0..143
        if (b0 + v < B) {
            const float4* src = x4 + (size_t)b0 * 2160 + v * 2160 + q;
            float4 t[15];
            #pragma unroll
            for (int s = 0; s < 15; ++s) t[s] = src[s * 144];
            float sx = 0.f, sy = 0.f, sz = 0.f, sw = 0.f;
            #pragma unroll
            for (int s = 0; s < 15; ++s) {
                sx += t[s].x; sy += t[s].y; sz += t[s].z; sw += t[s].w;
            }
            const float sc = 1.0f / 15.0f;
            xms[tid] = make_float4(sx * sc, sy * sc, sz * sc, sw * sc);
        } else {
            xms[tid] = make_float4(0.f, 0.f, 0.f, 0.f);
        }
    }
    __syncthreads();

    // ---- Phase 2: FC. 36 groups; group g -> rows o = g + 36k, k=0..2 ----
    const int grp = tid >> 4;     // 0..35
    const int l   = tid & 15;

    int oc[3];
    const float4* wr[3];
    #pragma unroll
    for (int k = 0; k < 3; ++k) {
        const int o = grp + 36 * k;
        oc[k] = (o < NOUT) ? o : 0;
        wr[k] = fcw4 + oc[k] * 144;
    }

    float acc[3][4] = {};

    #pragma unroll 3
    for (int jj = 0; jj < 9; ++jj) {
        const int q  = l + 16 * jj;
        const int cc = q / 9;                // channel of this quad

        float4 xv[4];
        #pragma unroll
        for (int v = 0; v < 4; ++v) xv[v] = xms[v * 144 + q];

        #pragma unroll
        for (int k = 0; k < 3; ++k) {
            const float4 w = wr[k][q];
            const float  a = attn_lds[oc[k] * 17 + cc];
            const float wx = a * w.x, wy = a * w.y, wz = a * w.z, ww = a * w.w;
            #pragma unroll
            for (int v = 0; v < 4; ++v) {
                acc[k][v] = fmaf(wx, xv[v].x, acc[k][v]);
                acc[k][v] = fmaf(wy, xv[v].y, acc[k][v]);
                acc[k][v] = fmaf(wz, xv[v].z, acc[k][v]);
                acc[k][v] = fmaf(ww, xv[v].w, acc[k][v]);
            }
        }
    }

    // transpose-reduce within 16 lanes: lane l<4 ends with volume l's sum
    #pragma unroll
    for (int k = 0; k < 3; ++k) {
        float rA[2];
        #pragma unroll
        for (int j = 0; j < 2; ++j) {
            const float lo = acc[k][2 * j], hi = acc[k][2 * j + 1];
            const bool  up = (l & 1);
            const float keep = up ? hi : lo;
            const float send = up ? lo : hi;
            rA[j] = keep + __shfl_xor(send, 1, 16);
        }
        float r1;
        {
            const float lo = rA[0], hi = rA[1];
            const bool  up = (l & 2);
            const float keep = up ? hi : lo;
            const float send = up ? lo : hi;
            r1 = keep + __shfl_xor(send, 2, 16);
        }
        r1 += __shfl_xor(r1, 4, 16);
        r1 += __shfl_xor(r1, 8, 16);         // lanes 0-3 hold vols 0-3

        const int o = grp + 36 * k;
        const int b = b0 + (l & 3);
        if (l < 4 && o < NOUT && b < B)
            out[(size_t)b * NOUT + o] = r1 + fcb[o];
    }
}

extern "C" void kernel_launch(void* const* d_in, const int* in_sizes, int n_in,
                              void* d_out, int out_size, void* d_ws, size_t ws_size,
                              hipStream_t stream) {
    const float* x   = (const float*)d_in[0];
    const float* dzh = (const float*)d_in[1];
    const float* dzl = (const float*)d_in[2];
    const float* fcw = (const float*)d_in[3];
    const float* fcb = (const float*)d_in[4];
    float* out = (float*)d_out;

    const int B = in_sizes[0] / (15 * 16 * 6 * 6);   // 4096
    const int blocks = (B + 3) / 4;                  // 1024

    hipLaunchKernelGGL(bodyavg_fused4, dim3(blocks), dim3(576), 0, stream,
                       reinterpret_cast<const float4*>(x), dzh, dzl,
                       reinterpret_cast<const float4*>(fcw), fcb, out, B);
}

// Round 7
// 34.980 us; speedup vs baseline: 1.4673x; 1.4673x over previous
//
#include <hip/hip_runtime.h>

#define NOUT 83
#define NHEART 27
#define NLUNG 28

// Block: 512 threads = 8 waves; wave w owns volume b0+w and scans its
// 2160 quads (33.75 KB) fully sequentially, 1 KB per step.
// Position (64*i + l) mod 144 has period 9 in i -> lane keeps acc[i%9]
// (static index), then merges into LDS with 9 read-add-writes.
// FC phase: 32 groups x 16 lanes, 3 rows x 8 vols each, transpose-reduce.
__global__ __launch_bounds__(512) void bodyavg_scan8(
    const float4* __restrict__ x4,   // [B*2160] quads
    const float* __restrict__ dzh,   // [27,16]
    const float* __restrict__ dzl,   // [28,16]
    const float4* __restrict__ fcw4, // [83,144] quads
    const float* __restrict__ fcb,   // [83]
    float* __restrict__ out,         // [B,83]
    int B)
{
    __shared__ float  attn_lds[NOUT * 17];
    __shared__ float4 xms[8 * 144];          // per-volume slice-SUM (not mean)

    const int tid = threadIdx.x;
    const int blk = blockIdx.x;
    const int b0  = blk * 8;

    // ---- Phase 0: channel softmax (1/15 of the slice-mean folded in) ----
    if (tid < NOUT) {
        const int o = tid;
        const float* row = (o < NHEART) ? (dzh + o * 16)
                                        : (dzl + ((o - NHEART) % NLUNG) * 16);
        float vals[16];
        #pragma unroll
        for (int c = 0; c < 16; ++c) vals[c] = row[c];
        float m = vals[0];
        #pragma unroll
        for (int c = 1; c < 16; ++c) m = fmaxf(m, vals[c]);
        float s = 0.f;
        #pragma unroll
        for (int c = 0; c < 16; ++c) { vals[c] = expf(vals[c] - m); s += vals[c]; }
        const float inv = (1.0f / s) * (1.0f / 15.0f);
        #pragma unroll
        for (int c = 0; c < 16; ++c) attn_lds[o * 17 + c] = vals[c] * inv;
    }

    const int w = tid >> 6;       // wave = volume slot 0..7
    const int l = tid & 63;
    const int b = b0 + w;

    // zero own wave's xms region (no barrier needed: only this wave RMWs it)
    {
        const float4 z = make_float4(0.f, 0.f, 0.f, 0.f);
        xms[w * 144 + l] = z;
        xms[w * 144 + l + 64] = z;
        if (l < 16) xms[w * 144 + l + 128] = z;
    }

    // ---- Phase 1: sequential scan of one volume per wave ----
    float4 acc[9];
    #pragma unroll
    for (int j = 0; j < 9; ++j) acc[j] = make_float4(0.f, 0.f, 0.f, 0.f);

    if (b < B) {
        const float4* src = x4 + (size_t)b * 2160 + l;
        // i = 0..26 in three 9-deep chunks (9 loads in flight each)
        #pragma unroll
        for (int c = 0; c < 3; ++c) {
            float4 t[9];
            #pragma unroll
            for (int u = 0; u < 9; ++u) t[u] = src[(c * 9 + u) * 64];
            #pragma unroll
            for (int u = 0; u < 9; ++u) {
                acc[u].x += t[u].x; acc[u].y += t[u].y;
                acc[u].z += t[u].z; acc[u].w += t[u].w;
            }
        }
        // tail i = 27..32 (full), j = i mod 9 = 0..5
        {
            float4 t[6];
            #pragma unroll
            for (int u = 0; u < 6; ++u) t[u] = src[(27 + u) * 64];
            #pragma unroll
            for (int u = 0; u < 6; ++u) {
                acc[u].x += t[u].x; acc[u].y += t[u].y;
                acc[u].z += t[u].z; acc[u].w += t[u].w;
            }
        }
        // i = 33: only 48 quads remain (2160 = 33*64 + 48), j = 6
        if (l < 48) {
            const float4 t = src[33 * 64];
            acc[6].x += t.x; acc[6].y += t.y; acc[6].z += t.z; acc[6].w += t.w;
        }
    }

    // merge: position of acc[j] is (64*j + l) mod 144; collisions across j
    // are resolved by sequential RMW (wave-lockstep => ordered within wave)
    #pragma unroll
    for (int j = 0; j < 9; ++j) {
        int p = (64 * j) % 144 + l;          // < 192
        if (p >= 144) p -= 144;
        const int idx = w * 144 + p;
        float4 cur = xms[idx];
        cur.x += acc[j].x; cur.y += acc[j].y;
        cur.z += acc[j].z; cur.w += acc[j].w;
        xms[idx] = cur;
    }

    __syncthreads();

    // ---- Phase 2: FC. 32 groups of 16 lanes; rows o = grp + 32k, k<3 ----
    const int grp = tid >> 4;     // 0..31
    const int ll  = tid & 15;

    int oc[3];
    const float4* wr[3];
    #pragma unroll
    for (int k = 0; k < 3; ++k) {
        const int o = grp + 32 * k;
        oc[k] = (o < NOUT) ? o : 0;
        wr[k] = fcw4 + oc[k] * 144;
    }

    float facc[3][8] = {};

    #pragma unroll 3
    for (int jj = 0; jj < 9; ++jj) {
        const int q  = ll + 16 * jj;
        const int cc = q / 9;                // channel of this quad

        float4 xv[8];
        #pragma unroll
        for (int v = 0; v < 8; ++v) xv[v] = xms[v * 144 + q];

        #pragma unroll
        for (int k = 0; k < 3; ++k) {
            const float4 wq = wr[k][q];
            const float  a  = attn_lds[oc[k] * 17 + cc];   // includes 1/15
            const float wx = a * wq.x, wy = a * wq.y, wz = a * wq.z, ww = a * wq.w;
            #pragma unroll
            for (int v = 0; v < 8; ++v) {
                facc[k][v] = fmaf(wx, xv[v].x, facc[k][v]);
                facc[k][v] = fmaf(wy, xv[v].y, facc[k][v]);
                facc[k][v] = fmaf(wz, xv[v].z, facc[k][v]);
                facc[k][v] = fmaf(ww, xv[v].w, facc[k][v]);
            }
        }
    }

    // transpose-reduce within 16 lanes: lane ll<8 ends with volume ll's sum
    #pragma unroll
    for (int k = 0; k < 3; ++k) {
        float r4[4];
        #pragma unroll
        for (int j = 0; j < 4; ++j) {
            const float lo = facc[k][2 * j], hi = facc[k][2 * j + 1];
            const bool  up = (ll & 1);
            const float keep = up ? hi : lo;
            const float send = up ? lo : hi;
            r4[j] = keep + __shfl_xor(send, 1, 16);
        }
        float r2[2];
        #pragma unroll
        for (int j = 0; j < 2; ++j) {
            const float lo = r4[2 * j], hi = r4[2 * j + 1];
            const bool  up = (ll & 2);
            const float keep = up ? hi : lo;
            const float send = up ? lo : hi;
            r2[j] = keep + __shfl_xor(send, 2, 16);
        }
        float r1;
        {
            const float lo = r2[0], hi = r2[1];
            const bool  up = (ll & 4);
            const float keep = up ? hi : lo;
            const float send = up ? lo : hi;
            r1 = keep + __shfl_xor(send, 4, 16);
        }
        r1 += __shfl_xor(r1, 8, 16);         // lanes 0-7 hold vols 0-7

        const int o = grp + 32 * k;
        const int bb = b0 + (ll & 7);
        if (ll < 8 && o < NOUT && bb < B)
            out[(size_t)bb * NOUT + o] = r1 + fcb[o];
    }
}

extern "C" void kernel_launch(void* const* d_in, const int* in_sizes, int n_in,
                              void* d_out, int out_size, void* d_ws, size_t ws_size,
                              hipStream_t stream) {
    const float* x   = (const float*)d_in[0];
    const float* dzh = (const float*)d_in[1];
    const float* dzl = (const float*)d_in[2];
    const float* fcw = (const float*)d_in[3];
    const float* fcb = (const float*)d_in[4];
    float* out = (float*)d_out;

    const int B = in_sizes[0] / (15 * 16 * 6 * 6);   // 4096
    const int blocks = (B + 7) / 8;                  // 512

    hipLaunchKernelGGL(bodyavg_scan8, dim3(blocks), dim3(512), 0, stream,
                       reinterpret_cast<const float4*>(x), dzh, dzl,
                       reinterpret_cast<const float4*>(fcw), fcb, out, B);
}